// Round 5
// baseline (529.100 us; speedup 1.0000x reference)
//
#include <hip/hip_runtime.h>
#include <hip/hip_bf16.h>
#include <stdint.h>

#define B_ 32
#define S_ 512
#define D_ 1024
#define F_ 4096
#define N_ (B_*S_)      // 16384 rows
#define E_ 8
#define ALPHA_ 2.0f

#define LDA1 1088       // D + 64 (32 lora cols + 32 pad)
#define LDA2 4160       // F + 64

typedef __hip_bfloat16 bf16;
typedef __attribute__((ext_vector_type(8))) short short8;
typedef __attribute__((ext_vector_type(8))) __bf16 bf16x8;
typedef __attribute__((ext_vector_type(4))) float f32x4;

__device__ __forceinline__ f32x4 mfma_bf16(short8 a, short8 b, f32x4 c) {
    return __builtin_amdgcn_mfma_f32_16x16x32_bf16(
        __builtin_bit_cast(bf16x8, a), __builtin_bit_cast(bf16x8, b), c, 0, 0, 0);
}

__device__ __forceinline__ void gload_lds16(const void* g, void* l) {
    __builtin_amdgcn_global_load_lds((const __attribute__((address_space(1))) void*)g,
                                     (__attribute__((address_space(3))) void*)l, 16, 0, 0);
}

__device__ __forceinline__ unsigned pack2(float a, float b) {
    unsigned short x = __builtin_bit_cast(unsigned short, __float2bfloat16(a));
    unsigned short y = __builtin_bit_cast(unsigned short, __float2bfloat16(b));
    return (unsigned)x | ((unsigned)y << 16);
}
__device__ __forceinline__ uint2 pack4(float4 v) {
    return make_uint2(pack2(v.x, v.y), pack2(v.z, v.w));
}

// ---------------------------------------------------------------------------
// Weight prep (unchanged - verified)
// ---------------------------------------------------------------------------
__global__ __launch_bounds__(256) void prep_w_kernel(
    const float* __restrict__ wi, const float* __restrict__ wo,
    const float* __restrict__ cwia, const float* __restrict__ cwib,
    const float* __restrict__ cwoa, const float* __restrict__ cwob,
    const float* __restrict__ ewia, const float* __restrict__ ewib,
    const float* __restrict__ ewoa, const float* __restrict__ ewob,
    bf16* __restrict__ wi_b, bf16* __restrict__ wo_b,
    bf16* __restrict__ ex1, bf16* __restrict__ ex2,
    bf16* __restrict__ wilo, bf16* __restrict__ wolo)
{
    const int tid0 = blockIdx.x * blockDim.x + threadIdx.x;
    const int stride = gridDim.x * blockDim.x;

    for (int i = tid0; i < F_*D_/4; i += stride) {
        ((uint2*)wi_b)[i] = pack4(((const float4*)wi)[i]);
        ((uint2*)wo_b)[i] = pack4(((const float4*)wo)[i]);
    }
    for (int i = tid0; i < E_*F_*16; i += stride) {
        int e = i >> 16; int rem = i & 0xFFFF; int f = rem >> 4; int r = rem & 15;
        bf16* dst = ex1 + (((size_t)e*F_ + f) << 6);
        dst[r]      = __float2bfloat16(cwib[f*16 + r]);
        dst[16 + r] = __float2bfloat16(ewib[(((size_t)e*F_ + f) << 4) + r]);
        dst[32 + r] = __float2bfloat16(0.f);
        dst[48 + r] = __float2bfloat16(0.f);
    }
    for (int i = tid0; i < E_*D_*16; i += stride) {
        int e = i >> 14; int rem = i & 0x3FFF; int d = rem >> 4; int r = rem & 15;
        bf16* dst = ex2 + (((size_t)e*D_ + d) << 6);
        dst[r]      = __float2bfloat16(cwob[d*16 + r]);
        dst[16 + r] = __float2bfloat16(ewob[(((size_t)e*D_ + d) << 4) + r]);
        dst[32 + r] = __float2bfloat16(0.f);
        dst[48 + r] = __float2bfloat16(0.f);
    }
    for (int i = tid0; i < E_*32*(D_/4); i += stride) {
        int e = i / (32*(D_/4)); int rem = i - e*(32*(D_/4));
        int r = rem / (D_/4); int c4 = (rem % (D_/4)) * 4;
        const float* src = (r < 16) ? (cwia + (size_t)r*D_ + c4)
                                    : (ewia + ((size_t)(e*16 + (r-16)))*D_ + c4);
        *(uint2*)(wilo + ((size_t)(e*32 + r))*D_ + c4) = pack4(*(const float4*)src);
    }
    for (int i = tid0; i < E_*32*(F_/4); i += stride) {
        int e = i / (32*(F_/4)); int rem = i - e*(32*(F_/4));
        int r = rem / (F_/4); int c4 = (rem % (F_/4)) * 4;
        const float* src = (r < 16) ? (cwoa + (size_t)r*F_ + c4)
                                    : (ewoa + ((size_t)(e*16 + (r-16)))*F_ + c4);
        *(uint2*)(wolo + ((size_t)(e*32 + r))*F_ + c4) = pack4(*(const float4*)src);
    }
}

__global__ __launch_bounds__(256) void prep_x_kernel(
    const float* __restrict__ x, bf16* __restrict__ A1)
{
    const int tid0 = blockIdx.x * blockDim.x + threadIdx.x;
    const int stride = gridDim.x * blockDim.x;
    for (int i = tid0; i < N_*(D_/4); i += stride) {
        int row = i >> 8; int c4 = (i & 255) << 2;
        float4 v = *(const float4*)(x + (size_t)i * 4);
        *(uint2*)(A1 + (size_t)row*LDA1 + c4) = pack4(v);
    }
    for (int i = tid0; i < N_*8; i += stride) {
        int row = i >> 3; int c = (i & 7) << 2;
        *(uint2*)(A1 + (size_t)row*LDA1 + 1056 + c) = make_uint2(0u, 0u);
    }
}

// ---------------------------------------------------------------------------
// Low-rank projection (unchanged - verified)
// ---------------------------------------------------------------------------
template<int K>
__global__ __launch_bounds__(256) void lowproj_kernel(
    const bf16* __restrict__ A, const bf16* __restrict__ W,
    const int* __restrict__ eids, bf16* __restrict__ Out,
    int lda, int kout)
{
    constexpr int BM = 64, BK = 64;
    __shared__ __align__(16) bf16 Asm[BM*BK];
    __shared__ __align__(16) bf16 Wsm[32*BK];

    const int tid = threadIdx.x;
    const int row0 = blockIdx.x * BM;
    const int e = eids[row0 >> 9];
    const int w = tid >> 6, lane = tid & 63;
    const int tr = tid >> 3, ts = tid & 7;
    const int lrow = lane & 15;
    const int lk16 = (lane >> 4) << 4;

    f32x4 acc[2] = {};

    int aoff, woff[2];
    { int r = w*16 + lrow; aoff = r*128 + (lk16 ^ ((r & 7) << 4)); }
    #pragma unroll
    for (int n = 0; n < 2; ++n) {
        int r = n*16 + lrow; woff[n] = r*128 + (lk16 ^ ((r & 7) << 4));
    }
    const bf16* Wp = W + (size_t)e * 32 * K;

    #pragma unroll 1
    for (int kt = 0; kt < K/BK; ++kt) {
        const int k0 = kt * BK;
        #pragma unroll
        for (int i = 0; i < 2; ++i) {
            int row = tr + 32*i;
            int slot = ts ^ (row & 7);
            gload_lds16(A + (size_t)(row0 + row)*lda + k0 + slot*8,
                        (char*)Asm + row*128 + ts*16);
        }
        {
            int row = tr;
            int slot = ts ^ (row & 7);
            gload_lds16(Wp + (size_t)row*K + k0 + slot*8,
                        (char*)Wsm + row*128 + ts*16);
        }
        __syncthreads();
        #pragma unroll
        for (int kk = 0; kk < 2; ++kk) {
            short8 a = *(const short8*)((const char*)Asm + (aoff ^ (kk << 6)));
            #pragma unroll
            for (int n = 0; n < 2; ++n) {
                short8 b = *(const short8*)((const char*)Wsm + (woff[n] ^ (kk << 6)));
                acc[n] = mfma_bf16(a, b, acc[n]);
            }
        }
        __syncthreads();
    }

    const int jrow = (lane >> 4) << 2;
    #pragma unroll
    for (int n = 0; n < 2; ++n) {
        #pragma unroll
        for (int j = 0; j < 4; ++j) {
            int r = row0 + w*16 + jrow + j;
            int c = n*16 + lrow;
            Out[(size_t)r*lda + kout + c] = __float2bfloat16(ALPHA_ * acc[n][j]);
        }
    }
    #pragma unroll
    for (int i = 0; i < 8; ++i) {
        int idx = tid*8 + i;
        int r = idx >> 5, c = idx & 31;
        Out[(size_t)(row0 + r)*lda + kout + 32 + c] = __float2bfloat16(0.f);
    }
}

// ---------------------------------------------------------------------------
// 256x256 GEMM, R2 structure (1 barrier/tile, no internal barriers) with the
// stage for tile t+1 moved to the TOP of tile t's body: buf^1's readers all
// finished at the t-1 boundary barrier, so staging at tile start is legal and
// gives a full-tile (~600-700 cyc) prefetch distance instead of ph3->end
// (~300 cyc). Tile-end __syncthreads (vmcnt0 drain) is then mostly satisfied.
// ---------------------------------------------------------------------------
#define DSREAD(base, off) (*(const short8*)((const char*)(base) + (off)))

#define STAGE4(gptr, ld, ldsbase)                                          \
    _Pragma("unroll")                                                      \
    for (int i_ = 0; i_ < 4; ++i_) {                                       \
        int row_ = tr + 64*i_;                                             \
        int slot_ = ts ^ (row_ & 7);                                       \
        gload_lds16((gptr) + (size_t)row_*(ld) + slot_*8,                  \
                    (char*)(ldsbase) + row_*128 + ts*16);                  \
    }

#define STAGE_TILE(KTN, AL, BL)                                            \
  { STAGE4(Ag + (size_t)(KTN)*64, LDAe, AL);                               \
    if ((KTN) < KMAIN_EL/64) { STAGE4(Bg + (size_t)(KTN)*64, LDBe, BL); }  \
    else                     { STAGE4(Bxg, 64, BL); } }

#define TILE_BODY(AC, BC, DOSTAGE, AN, BN, KTN)                            \
  {                                                                        \
    /* ph0: stage next tile FIRST - full-tile prefetch distance */         \
    if (DOSTAGE) { STAGE_TILE((KTN), AN, BN); }                            \
    short8 af[4][2]; short8 bq[4][2];                                      \
    /* ph1: A quad-row0 + B n0-1 -> q00 */                                 \
    _Pragma("unroll") for (int m = 0; m < 4; ++m)                          \
      _Pragma("unroll") for (int kk = 0; kk < 2; ++kk)                     \
        af[m][kk] = DSREAD(AC, aoff[m] ^ (kk << 6));                       \
    _Pragma("unroll") for (int n = 0; n < 2; ++n)                          \
      _Pragma("unroll") for (int kk = 0; kk < 2; ++kk)                     \
        bq[n][kk] = DSREAD(BC, boff[n] ^ (kk << 6));                       \
    __builtin_amdgcn_s_setprio(1);                                         \
    _Pragma("unroll") for (int m = 0; m < 4; ++m)                          \
      _Pragma("unroll") for (int n = 0; n < 2; ++n)                        \
        _Pragma("unroll") for (int kk = 0; kk < 2; ++kk)                   \
          acc[m][n] = mfma_bf16(af[m][kk], bq[n][kk], acc[m][n]);          \
    __builtin_amdgcn_s_setprio(0);                                         \
    /* ph2: B n2-3 -> q01 */                                               \
    _Pragma("unroll") for (int n = 2; n < 4; ++n)                          \
      _Pragma("unroll") for (int kk = 0; kk < 2; ++kk)                     \
        bq[n][kk] = DSREAD(BC, boff[n] ^ (kk << 6));                       \
    __builtin_amdgcn_s_setprio(1);                                         \
    _Pragma("unroll") for (int m = 0; m < 4; ++m)                          \
      _Pragma("unroll") for (int n = 2; n < 4; ++n)                        \
        _Pragma("unroll") for (int kk = 0; kk < 2; ++kk)                   \
          acc[m][n] = mfma_bf16(af[m][kk], bq[n][kk], acc[m][n]);          \
    __builtin_amdgcn_s_setprio(0);                                         \
    /* ph3: A quad-row1 -> q10 */                                          \
    _Pragma("unroll") for (int m = 0; m < 4; ++m)                          \
      _Pragma("unroll") for (int kk = 0; kk < 2; ++kk)                     \
        af[m][kk] = DSREAD(AC, aoff[m+4] ^ (kk << 6));                     \
    __builtin_amdgcn_s_setprio(1);                                         \
    _Pragma("unroll") for (int m = 0; m < 4; ++m)                          \
      _Pragma("unroll") for (int n = 0; n < 2; ++n)                        \
        _Pragma("unroll") for (int kk = 0; kk < 2; ++kk)                   \
          acc[m+4][n] = mfma_bf16(af[m][kk], bq[n][kk], acc[m+4][n]);      \
    __builtin_amdgcn_s_setprio(0);                                         \
    /* ph4: q11 */                                                         \
    __builtin_amdgcn_s_setprio(1);                                         \
    _Pragma("unroll") for (int m = 0; m < 4; ++m)                          \
      _Pragma("unroll") for (int n = 2; n < 4; ++n)                        \
        _Pragma("unroll") for (int kk = 0; kk < 2; ++kk)                   \
          acc[m+4][n] = mfma_bf16(af[m][kk], bq[n][kk], acc[m+4][n]);      \
    __builtin_amdgcn_s_setprio(0);                                         \
    __syncthreads();                                                       \
  }

template<int KMAIN_EL, int LDAe, int LDBe, int LDCe, int NCOLSe, bool RELU_BF16>
__global__ __launch_bounds__(512, 2) void gemm256_kernel(
    const bf16* __restrict__ A, const bf16* __restrict__ Bmain,
    const bf16* __restrict__ Bextra, const int* __restrict__ eids,
    void* __restrict__ C)
{
    constexpr int MT = N_/256;
    constexpr int NT = NCOLSe/256;
    constexpr int NWG = MT*NT;
    constexpr int KTILES = KMAIN_EL/64 + 1;
    static_assert((KTILES & 1) == 1, "pair loop + tail assumes odd KTILES");
    static_assert(NWG % 8 == 0, "xcd swizzle needs nwg%8==0");
    constexpr int CPX = NWG/8;

    __shared__ __align__(16) bf16 As[2][256*64];   // 2 x 32 KiB
    __shared__ __align__(16) bf16 Bs[2][256*64];   // 2 x 32 KiB

    const int bid = blockIdx.x;
    const int wg = (bid & 7) * CPX + (bid >> 3);
    const int mt = wg % MT, nt = wg / MT;
    const int arow0 = mt * 256, bcol0 = nt * 256;
    const int e = eids[arow0 >> 9];

    const int tid = threadIdx.x;
    const int lane = tid & 63;
    const int wid = tid >> 6;
    const int wm = wid >> 2, wn = wid & 3;
    const int tr = tid >> 3, ts = tid & 7;

    const bf16* Ag  = A + (size_t)arow0 * LDAe;
    const bf16* Bg  = Bmain + (size_t)bcol0 * LDBe;
    const bf16* Bxg = Bextra + ((size_t)e * NCOLSe + bcol0) * 64;

    int aoff[8], boff[4];
    const int lk16 = (lane >> 4) << 4;
    #pragma unroll
    for (int m = 0; m < 8; ++m) {
        int r = wm*128 + m*16 + (lane & 15);
        aoff[m] = r*128 + (lk16 ^ ((r & 7) << 4));
    }
    #pragma unroll
    for (int n = 0; n < 4; ++n) {
        int r = wn*64 + n*16 + (lane & 15);
        boff[n] = r*128 + (lk16 ^ ((r & 7) << 4));
    }

    f32x4 acc[8][4] = {};

    // prologue: stage tile 0, full drain once
    STAGE_TILE(0, As[0], Bs[0]);
    __syncthreads();

    #pragma unroll 1
    for (int t = 0; t < KTILES - 1; t += 2) {
        TILE_BODY(As[0], Bs[0], true, As[1], Bs[1], t + 1);
        TILE_BODY(As[1], Bs[1], true, As[0], Bs[0], t + 2);
    }
    TILE_BODY(As[0], Bs[0], false, As[1], Bs[1], 0);

    const int jrow = (lane >> 4) << 2;
    if constexpr (RELU_BF16) {
        bf16* Cb = (bf16*)C;
        #pragma unroll
        for (int m = 0; m < 8; ++m)
            #pragma unroll
            for (int j = 0; j < 4; ++j) {
                size_t rbase = (size_t)(arow0 + wm*128 + m*16 + jrow + j) * LDCe;
                #pragma unroll
                for (int n = 0; n < 4; ++n) {
                    float v = acc[m][n][j];
                    v = v > 0.f ? v : 0.f;
                    Cb[rbase + bcol0 + wn*64 + n*16 + (lane & 15)] = __float2bfloat16(v);
                }
            }
    } else {
        float* Cf = (float*)C;
        #pragma unroll
        for (int m = 0; m < 8; ++m)
            #pragma unroll
            for (int j = 0; j < 4; ++j) {
                size_t rbase = (size_t)(arow0 + wm*128 + m*16 + jrow + j) * LDCe;
                #pragma unroll
                for (int n = 0; n < 4; ++n)
                    Cf[rbase + bcol0 + wn*64 + n*16 + (lane & 15)] = acc[m][n][j];
            }
    }
}

// ---------------------------------------------------------------------------
extern "C" void kernel_launch(void* const* d_in, const int* in_sizes, int n_in,
                              void* d_out, int out_size, void* d_ws, size_t ws_size,
                              hipStream_t stream)
{
    const float* x    = (const float*)d_in[0];
    const int*   eids = (const int*)d_in[1];
    const float* wi   = (const float*)d_in[2];
    const float* wo   = (const float*)d_in[3];
    const float* cwia = (const float*)d_in[4];
    const float* cwib = (const float*)d_in[5];
    const float* cwoa = (const float*)d_in[6];
    const float* cwob = (const float*)d_in[7];
    const float* ewia = (const float*)d_in[8];
    const float* ewib = (const float*)d_in[9];
    const float* ewoa = (const float*)d_in[10];
    const float* ewob = (const float*)d_in[11];

    char* p = (char*)d_ws;
    bf16* A1   = (bf16*)p; p += (size_t)N_*LDA1*sizeof(bf16);
    bf16* A2   = (bf16*)p; p += (size_t)N_*LDA2*sizeof(bf16);
    bf16* wi_b = (bf16*)p; p += (size_t)F_*D_*sizeof(bf16);
    bf16* wo_b = (bf16*)p; p += (size_t)D_*F_*sizeof(bf16);
    bf16* ex1  = (bf16*)p; p += (size_t)E_*F_*64*sizeof(bf16);
    bf16* ex2  = (bf16*)p; p += (size_t)E_*D_*64*sizeof(bf16);
    bf16* wilo = (bf16*)p; p += (size_t)E_*32*D_*sizeof(bf16);
    bf16* wolo = (bf16*)p; p += (size_t)E_*32*F_*sizeof(bf16);

    prep_w_kernel<<<dim3(512), dim3(256), 0, stream>>>(
        wi, wo, cwia, cwib, cwoa, cwob, ewia, ewib, ewoa, ewob,
        wi_b, wo_b, ex1, ex2, wilo, wolo);

    prep_x_kernel<<<dim3(2048), dim3(256), 0, stream>>>(x, A1);

    lowproj_kernel<D_><<<dim3(N_/64), dim3(256), 0, stream>>>(
        A1, wilo, eids, A1, LDA1, D_);

    // GEMM1: [N x 1088] * [4096 x 1088]^T -> relu -> A2 bf16 cols 0..4095
    gemm256_kernel<D_, LDA1, D_, LDA2, F_, true>
        <<<dim3((N_/256)*(F_/256)), dim3(512), 0, stream>>>(A1, wi_b, ex1, eids, A2);

    lowproj_kernel<F_><<<dim3(N_/64), dim3(256), 0, stream>>>(
        A2, wolo, eids, A2, LDA2, F_);

    // GEMM2: [N x 4160] * [1024 x 4160]^T -> d_out f32
    gemm256_kernel<F_, LDA2, F_, D_, D_, false>
        <<<dim3((N_/256)*(D_/256)), dim3(512), 0, stream>>>(A2, wo_b, ex2, eids, d_out);

    (void)in_sizes; (void)n_in; (void)out_size; (void)ws_size;
}

// Round 6
// 471.104 us; speedup vs baseline: 1.1231x; 1.1231x over previous
//
#include <hip/hip_runtime.h>
#include <hip/hip_bf16.h>
#include <stdint.h>

#define B_ 32
#define S_ 512
#define D_ 1024
#define F_ 4096
#define N_ (B_*S_)      // 16384 rows
#define E_ 8
#define ALPHA_ 2.0f

#define LDA1 1088       // D + 64 (32 lora cols + 32 pad)
#define LDA2 4160       // F + 64

typedef __hip_bfloat16 bf16;
typedef __attribute__((ext_vector_type(8))) short short8;
typedef __attribute__((ext_vector_type(8))) __bf16 bf16x8;
typedef __attribute__((ext_vector_type(4))) float f32x4;

__device__ __forceinline__ f32x4 mfma_bf16(short8 a, short8 b, f32x4 c) {
    return __builtin_amdgcn_mfma_f32_16x16x32_bf16(
        __builtin_bit_cast(bf16x8, a), __builtin_bit_cast(bf16x8, b), c, 0, 0, 0);
}

__device__ __forceinline__ void gload_lds16(const void* g, void* l) {
    __builtin_amdgcn_global_load_lds((const __attribute__((address_space(1))) void*)g,
                                     (__attribute__((address_space(3))) void*)l, 16, 0, 0);
}

__device__ __forceinline__ unsigned pack2(float a, float b) {
    unsigned short x = __builtin_bit_cast(unsigned short, __float2bfloat16(a));
    unsigned short y = __builtin_bit_cast(unsigned short, __float2bfloat16(b));
    return (unsigned)x | ((unsigned)y << 16);
}
__device__ __forceinline__ uint2 pack4(float4 v) {
    return make_uint2(pack2(v.x, v.y), pack2(v.z, v.w));
}

// ---------------------------------------------------------------------------
// Weight prep (unchanged - verified)
// ---------------------------------------------------------------------------
__global__ __launch_bounds__(256) void prep_w_kernel(
    const float* __restrict__ wi, const float* __restrict__ wo,
    const float* __restrict__ cwia, const float* __restrict__ cwib,
    const float* __restrict__ cwoa, const float* __restrict__ cwob,
    const float* __restrict__ ewia, const float* __restrict__ ewib,
    const float* __restrict__ ewoa, const float* __restrict__ ewob,
    bf16* __restrict__ wi_b, bf16* __restrict__ wo_b,
    bf16* __restrict__ ex1, bf16* __restrict__ ex2,
    bf16* __restrict__ wilo, bf16* __restrict__ wolo)
{
    const int tid0 = blockIdx.x * blockDim.x + threadIdx.x;
    const int stride = gridDim.x * blockDim.x;

    for (int i = tid0; i < F_*D_/4; i += stride) {
        ((uint2*)wi_b)[i] = pack4(((const float4*)wi)[i]);
        ((uint2*)wo_b)[i] = pack4(((const float4*)wo)[i]);
    }
    for (int i = tid0; i < E_*F_*16; i += stride) {
        int e = i >> 16; int rem = i & 0xFFFF; int f = rem >> 4; int r = rem & 15;
        bf16* dst = ex1 + (((size_t)e*F_ + f) << 6);
        dst[r]      = __float2bfloat16(cwib[f*16 + r]);
        dst[16 + r] = __float2bfloat16(ewib[(((size_t)e*F_ + f) << 4) + r]);
        dst[32 + r] = __float2bfloat16(0.f);
        dst[48 + r] = __float2bfloat16(0.f);
    }
    for (int i = tid0; i < E_*D_*16; i += stride) {
        int e = i >> 14; int rem = i & 0x3FFF; int d = rem >> 4; int r = rem & 15;
        bf16* dst = ex2 + (((size_t)e*D_ + d) << 6);
        dst[r]      = __float2bfloat16(cwob[d*16 + r]);
        dst[16 + r] = __float2bfloat16(ewob[(((size_t)e*D_ + d) << 4) + r]);
        dst[32 + r] = __float2bfloat16(0.f);
        dst[48 + r] = __float2bfloat16(0.f);
    }
    for (int i = tid0; i < E_*32*(D_/4); i += stride) {
        int e = i / (32*(D_/4)); int rem = i - e*(32*(D_/4));
        int r = rem / (D_/4); int c4 = (rem % (D_/4)) * 4;
        const float* src = (r < 16) ? (cwia + (size_t)r*D_ + c4)
                                    : (ewia + ((size_t)(e*16 + (r-16)))*D_ + c4);
        *(uint2*)(wilo + ((size_t)(e*32 + r))*D_ + c4) = pack4(*(const float4*)src);
    }
    for (int i = tid0; i < E_*32*(F_/4); i += stride) {
        int e = i / (32*(F_/4)); int rem = i - e*(32*(F_/4));
        int r = rem / (F_/4); int c4 = (rem % (F_/4)) * 4;
        const float* src = (r < 16) ? (cwoa + (size_t)r*F_ + c4)
                                    : (ewoa + ((size_t)(e*16 + (r-16)))*F_ + c4);
        *(uint2*)(wolo + ((size_t)(e*32 + r))*F_ + c4) = pack4(*(const float4*)src);
    }
}

__global__ __launch_bounds__(256) void prep_x_kernel(
    const float* __restrict__ x, bf16* __restrict__ A1)
{
    const int tid0 = blockIdx.x * blockDim.x + threadIdx.x;
    const int stride = gridDim.x * blockDim.x;
    for (int i = tid0; i < N_*(D_/4); i += stride) {
        int row = i >> 8; int c4 = (i & 255) << 2;
        float4 v = *(const float4*)(x + (size_t)i * 4);
        *(uint2*)(A1 + (size_t)row*LDA1 + c4) = pack4(v);
    }
    for (int i = tid0; i < N_*8; i += stride) {
        int row = i >> 3; int c = (i & 7) << 2;
        *(uint2*)(A1 + (size_t)row*LDA1 + 1056 + c) = make_uint2(0u, 0u);
    }
}

// ---------------------------------------------------------------------------
// Low-rank projection (unchanged - verified)
// ---------------------------------------------------------------------------
template<int K>
__global__ __launch_bounds__(256) void lowproj_kernel(
    const bf16* __restrict__ A, const bf16* __restrict__ W,
    const int* __restrict__ eids, bf16* __restrict__ Out,
    int lda, int kout)
{
    constexpr int BM = 64, BK = 64;
    __shared__ __align__(16) bf16 Asm[BM*BK];
    __shared__ __align__(16) bf16 Wsm[32*BK];

    const int tid = threadIdx.x;
    const int row0 = blockIdx.x * BM;
    const int e = eids[row0 >> 9];
    const int w = tid >> 6, lane = tid & 63;
    const int tr = tid >> 3, ts = tid & 7;
    const int lrow = lane & 15;
    const int lk16 = (lane >> 4) << 4;

    f32x4 acc[2] = {};

    int aoff, woff[2];
    { int r = w*16 + lrow; aoff = r*128 + (lk16 ^ ((r & 7) << 4)); }
    #pragma unroll
    for (int n = 0; n < 2; ++n) {
        int r = n*16 + lrow; woff[n] = r*128 + (lk16 ^ ((r & 7) << 4));
    }
    const bf16* Wp = W + (size_t)e * 32 * K;

    #pragma unroll 1
    for (int kt = 0; kt < K/BK; ++kt) {
        const int k0 = kt * BK;
        #pragma unroll
        for (int i = 0; i < 2; ++i) {
            int row = tr + 32*i;
            int slot = ts ^ (row & 7);
            gload_lds16(A + (size_t)(row0 + row)*lda + k0 + slot*8,
                        (char*)Asm + row*128 + ts*16);
        }
        {
            int row = tr;
            int slot = ts ^ (row & 7);
            gload_lds16(Wp + (size_t)row*K + k0 + slot*8,
                        (char*)Wsm + row*128 + ts*16);
        }
        __syncthreads();
        #pragma unroll
        for (int kk = 0; kk < 2; ++kk) {
            short8 a = *(const short8*)((const char*)Asm + (aoff ^ (kk << 6)));
            #pragma unroll
            for (int n = 0; n < 2; ++n) {
                short8 b = *(const short8*)((const char*)Wsm + (woff[n] ^ (kk << 6)));
                acc[n] = mfma_bf16(a, b, acc[n]);
            }
        }
        __syncthreads();
    }

    const int jrow = (lane >> 4) << 2;
    #pragma unroll
    for (int n = 0; n < 2; ++n) {
        #pragma unroll
        for (int j = 0; j < 4; ++j) {
            int r = row0 + w*16 + jrow + j;
            int c = n*16 + lrow;
            Out[(size_t)r*lda + kout + c] = __float2bfloat16(ALPHA_ * acc[n][j]);
        }
    }
    #pragma unroll
    for (int i = 0; i < 8; ++i) {
        int idx = tid*8 + i;
        int r = idx >> 5, c = idx & 31;
        Out[(size_t)(row0 + r)*lda + kout + 32 + c] = __float2bfloat16(0.f);
    }
}

// ---------------------------------------------------------------------------
// 256x256 GEMM, m201-style fine-grained schedule (T2+T3+T4+T5+T1):
//  - Half-tile staging: A-halves by row-bit6, B-halves by row-bit5, so that
//    af_lo in A-h0, af_hi in A-h1, bq_lo in B-h0, bq_hi in B-h1 for ALL waves.
//  - Stage order for tile t+1 during tile t: A-h0, B-h0, B-h1, A-h1
//    (2 gload_lds/thread each). Consumption: ph1 {A-h0,B-h0}, ph2 +B-h1,
//    ph3 +A-h1, ph4 none.
//  - Ledger: uniform s_waitcnt vmcnt(4) at ph1/ph2/ph4 boundaries; 4 loads
//    always in flight across each tile boundary; no vmcnt(0) in main loop.
//  - 3 barriers/tile, each preceded by the counted wait ("memory" clobber
//    keeps C++ ds_reads from hoisting above).  setprio(1) per 16-MFMA cluster.
// ---------------------------------------------------------------------------
#define DSREAD(base, off) (*(const short8*)((const char*)(base) + (off)))
#define VMW4 asm volatile("s_waitcnt vmcnt(4)" ::: "memory")
#define VMW2 asm volatile("s_waitcnt vmcnt(2)" ::: "memory")
#define VMW0 asm volatile("s_waitcnt vmcnt(0)" ::: "memory")
#define VMNONE (void)0
#define BAR __builtin_amdgcn_s_barrier()

// A half h: rows {tr + 64h, tr + 64h + 128}  (bit6 of row == h)
#define STAGE_A_HALF(KTN, AL, h)                                           \
  { const bf16* gpA_ = Ag + (size_t)(KTN)*64;                              \
    int rA_ = tr + 64*(h);                                                 \
    int sA_ = ts ^ (rA_ & 7);                                              \
    gload_lds16(gpA_ + (size_t)rA_*LDAe + sA_*8,                           \
                (char*)(AL) + rA_*128 + ts*16);                            \
    int rA2_ = rA_ + 128;                                                  \
    gload_lds16(gpA_ + (size_t)rA2_*LDAe + sA_*8,                          \
                (char*)(AL) + rA2_*128 + ts*16); }

// B half h: rows {(tr&31) + 64*(tr>>5) + 32h, +128}  (bit5 of row == h)
#define STAGE_B_HALF(KTN, BL, h)                                           \
  { const bf16* gpB_; int bldB_; int bkB_;                                 \
    if ((KTN) < KMAIN_EL/64) { gpB_ = Bg; bldB_ = LDBe; bkB_ = (KTN)*64; } \
    else                     { gpB_ = Bxg; bldB_ = 64; bkB_ = 0; }         \
    int rB_ = (tr & 31) + 64*(tr >> 5) + 32*(h);                           \
    int sB_ = ts ^ (rB_ & 7);                                              \
    gload_lds16(gpB_ + (size_t)rB_*bldB_ + bkB_ + sB_*8,                   \
                (char*)(BL) + rB_*128 + ts*16);                            \
    int rB2_ = rB_ + 128;                                                  \
    gload_lds16(gpB_ + (size_t)rB2_*bldB_ + bkB_ + sB_*8,                  \
                (char*)(BL) + rB2_*128 + ts*16); }

#define RD_AF(dst, AC, base)                                               \
  _Pragma("unroll") for (int m_ = 0; m_ < 4; ++m_)                         \
    _Pragma("unroll") for (int k_ = 0; k_ < 2; ++k_)                       \
      dst[m_][k_] = DSREAD(AC, aoff[(base)+m_] ^ (k_ << 6));

#define RD_BQ(dst, BC, base)                                               \
  _Pragma("unroll") for (int n_ = 0; n_ < 2; ++n_)                         \
    _Pragma("unroll") for (int k_ = 0; k_ < 2; ++k_)                       \
      dst[n_][k_] = DSREAD(BC, boff[(base)+n_] ^ (k_ << 6));

#define MFMA16(afr, bqr, mb, nb)                                           \
  __builtin_amdgcn_s_setprio(1);                                           \
  _Pragma("unroll") for (int m_ = 0; m_ < 4; ++m_)                         \
    _Pragma("unroll") for (int n_ = 0; n_ < 2; ++n_)                       \
      _Pragma("unroll") for (int k_ = 0; k_ < 2; ++k_)                     \
        acc[(mb)+m_][(nb)+n_] =                                            \
            mfma_bf16(afr[m_][k_], bqr[n_][k_], acc[(mb)+m_][(nb)+n_]);    \
  __builtin_amdgcn_s_setprio(0);

#define TILE8(AC, BC, DOSTAGE, AN, BN, KTN, W1, W2, W4)                    \
  {                                                                        \
    short8 afl[4][2], afh[4][2], bql[2][2], bqh[2][2];                     \
    /* ph1: reads assured by previous boundary wait */                     \
    RD_AF(afl, AC, 0); RD_BQ(bql, BC, 0);                                  \
    if (DOSTAGE) { STAGE_A_HALF(KTN, AN, 0); }                             \
    W1; BAR;                                                               \
    MFMA16(afl, bql, 0, 0);                                                \
    /* ph2 */                                                              \
    RD_BQ(bqh, BC, 2);                                                     \
    if (DOSTAGE) { STAGE_B_HALF(KTN, BN, 0); }                             \
    W2; BAR;                                                               \
    MFMA16(afl, bqh, 0, 2);                                                \
    /* ph3+ph4 */                                                          \
    RD_AF(afh, AC, 4);                                                     \
    if (DOSTAGE) { STAGE_B_HALF(KTN, BN, 1); }                             \
    MFMA16(afh, bql, 4, 0);                                                \
    if (DOSTAGE) { STAGE_A_HALF(KTN, AN, 1); }                             \
    W4; BAR;                                                               \
    MFMA16(afh, bqh, 4, 2);                                                \
  }

template<int KMAIN_EL, int LDAe, int LDBe, int LDCe, int NCOLSe, bool RELU_BF16>
__global__ __launch_bounds__(512, 2) void gemm256_kernel(
    const bf16* __restrict__ A, const bf16* __restrict__ Bmain,
    const bf16* __restrict__ Bextra, const int* __restrict__ eids,
    void* __restrict__ C)
{
    constexpr int MT = N_/256;
    constexpr int NT = NCOLSe/256;
    constexpr int NWG = MT*NT;
    constexpr int KTILES = KMAIN_EL/64 + 1;
    static_assert((KTILES & 1) == 1, "pair loop + tail assumes odd KTILES");
    static_assert(NWG % 8 == 0, "xcd swizzle needs nwg%8==0");
    constexpr int CPX = NWG/8;

    __shared__ __align__(16) bf16 As[2][256*64];   // 2 x 32 KiB
    __shared__ __align__(16) bf16 Bs[2][256*64];   // 2 x 32 KiB

    const int bid = blockIdx.x;
    const int wg = (bid & 7) * CPX + (bid >> 3);
    const int mt = wg % MT, nt = wg / MT;
    const int arow0 = mt * 256, bcol0 = nt * 256;
    const int e = eids[arow0 >> 9];

    const int tid = threadIdx.x;
    const int lane = tid & 63;
    const int wid = tid >> 6;
    const int wm = wid >> 2, wn = wid & 3;
    const int tr = tid >> 3, ts = tid & 7;

    const bf16* Ag  = A + (size_t)arow0 * LDAe;
    const bf16* Bg  = Bmain + (size_t)bcol0 * LDBe;
    const bf16* Bxg = Bextra + ((size_t)e * NCOLSe + bcol0) * 64;

    int aoff[8], boff[4];
    const int lk16 = (lane >> 4) << 4;
    #pragma unroll
    for (int m = 0; m < 8; ++m) {
        int r = wm*128 + m*16 + (lane & 15);
        aoff[m] = r*128 + (lk16 ^ ((r & 7) << 4));
    }
    #pragma unroll
    for (int n = 0; n < 4; ++n) {
        int r = wn*64 + n*16 + (lane & 15);
        boff[n] = r*128 + (lk16 ^ ((r & 7) << 4));
    }

    f32x4 acc[8][4] = {};

    // prologue: stage tile 0 halves in consumption-stagger order, counted wait
    STAGE_A_HALF(0, As[0], 0);
    STAGE_B_HALF(0, Bs[0], 0);
    STAGE_B_HALF(0, Bs[0], 1);
    STAGE_A_HALF(0, As[0], 1);
    VMW4; BAR;   // A-h0,B-h0 of tile0 landed; B-h1,A-h1 may fly

    #pragma unroll 1
    for (int t = 0; t < KTILES - 1; t += 2) {
        TILE8(As[0], Bs[0], true, As[1], Bs[1], t + 1, VMW4, VMW4, VMW4);
        TILE8(As[1], Bs[1], true, As[0], Bs[0], t + 2, VMW4, VMW4, VMW4);
    }
    // tail tile (no staging): drains 2 -> 0
    TILE8(As[0], Bs[0], false, As[1], Bs[1], 0, VMW2, VMW0, VMNONE);

    const int jrow = (lane >> 4) << 2;
    if constexpr (RELU_BF16) {
        bf16* Cb = (bf16*)C;
        #pragma unroll
        for (int m = 0; m < 8; ++m)
            #pragma unroll
            for (int j = 0; j < 4; ++j) {
                size_t rbase = (size_t)(arow0 + wm*128 + m*16 + jrow + j) * LDCe;
                #pragma unroll
                for (int n = 0; n < 4; ++n) {
                    float v = acc[m][n][j];
                    v = v > 0.f ? v : 0.f;
                    Cb[rbase + bcol0 + wn*64 + n*16 + (lane & 15)] = __float2bfloat16(v);
                }
            }
    } else {
        float* Cf = (float*)C;
        #pragma unroll
        for (int m = 0; m < 8; ++m)
            #pragma unroll
            for (int j = 0; j < 4; ++j) {
                size_t rbase = (size_t)(arow0 + wm*128 + m*16 + jrow + j) * LDCe;
                #pragma unroll
                for (int n = 0; n < 4; ++n)
                    Cf[rbase + bcol0 + wn*64 + n*16 + (lane & 15)] = acc[m][n][j];
            }
    }
}

// ---------------------------------------------------------------------------
extern "C" void kernel_launch(void* const* d_in, const int* in_sizes, int n_in,
                              void* d_out, int out_size, void* d_ws, size_t ws_size,
                              hipStream_t stream)
{
    const float* x    = (const float*)d_in[0];
    const int*   eids = (const int*)d_in[1];
    const float* wi   = (const float*)d_in[2];
    const float* wo   = (const float*)d_in[3];
    const float* cwia = (const float*)d_in[4];
    const float* cwib = (const float*)d_in[5];
    const float* cwoa = (const float*)d_in[6];
    const float* cwob = (const float*)d_in[7];
    const float* ewia = (const float*)d_in[8];
    const float* ewib = (const float*)d_in[9];
    const float* ewoa = (const float*)d_in[10];
    const float* ewob = (const float*)d_in[11];

    char* p = (char*)d_ws;
    bf16* A1   = (bf16*)p; p += (size_t)N_*LDA1*sizeof(bf16);
    bf16* A2   = (bf16*)p; p += (size_t)N_*LDA2*sizeof(bf16);
    bf16* wi_b = (bf16*)p; p += (size_t)F_*D_*sizeof(bf16);
    bf16* wo_b = (bf16*)p; p += (size_t)D_*F_*sizeof(bf16);
    bf16* ex1  = (bf16*)p; p += (size_t)E_*F_*64*sizeof(bf16);
    bf16* ex2  = (bf16*)p; p += (size_t)E_*D_*64*sizeof(bf16);
    bf16* wilo = (bf16*)p; p += (size_t)E_*32*D_*sizeof(bf16);
    bf16* wolo = (bf16*)p; p += (size_t)E_*32*F_*sizeof(bf16);

    prep_w_kernel<<<dim3(512), dim3(256), 0, stream>>>(
        wi, wo, cwia, cwib, cwoa, cwob, ewia, ewib, ewoa, ewob,
        wi_b, wo_b, ex1, ex2, wilo, wolo);

    prep_x_kernel<<<dim3(2048), dim3(256), 0, stream>>>(x, A1);

    lowproj_kernel<D_><<<dim3(N_/64), dim3(256), 0, stream>>>(
        A1, wilo, eids, A1, LDA1, D_);

    // GEMM1: [N x 1088] * [4096 x 1088]^T -> relu -> A2 bf16 cols 0..4095
    gemm256_kernel<D_, LDA1, D_, LDA2, F_, true>
        <<<dim3((N_/256)*(F_/256)), dim3(512), 0, stream>>>(A1, wi_b, ex1, eids, A2);

    lowproj_kernel<F_><<<dim3(N_/64), dim3(256), 0, stream>>>(
        A2, wolo, eids, A2, LDA2, F_);

    // GEMM2: [N x 4160] * [1024 x 4160]^T -> d_out f32
    gemm256_kernel<F_, LDA2, F_, D_, D_, false>
        <<<dim3((N_/256)*(D_/256)), dim3(512), 0, stream>>>(A2, wo_b, ex2, eids, d_out);

    (void)in_sizes; (void)n_in; (void)out_size; (void)ws_size;
}